// Round 6
// baseline (323.858 us; speedup 1.0000x reference)
//
#include <hip/hip_runtime.h>

// N3Tree query, fully-refined octree (N=2, REFINE=6, DATA_DIM=16).
//
// R7 = R6 + sequential L6 warm fused into the table pass.
// R6 recap: tbl[c5] = sum of L0..L5 path (16.8 MB, coalesced build), query
// in ORIGINAL qid order does 2 random 64 B reads (tbl[M>>3], L6[M]) + NT
// coalesced out write. Measured ~92 us kernel time (dur 288.7).
// Remaining wall: the harness poison-fill (599 MB) evicts L3 each
// iteration, so the query's ~1.16M unique random L6 line fetches come
// from HBM at scattered-line rate (~2 TB/s, R3/R4 lesson) ~= 35-40 us.
// Fix: table pass also STREAMS all of L6 (134 MB, sequential, ~21 us at
// 6.3 TB/s) with keep-alive asm so the random-read set (L6 134 + tbl 17
// = 151 MB < 256 MB L3) is L3-resident when the query runs; idx/out stay
// NT (no-allocate) so the streams don't evict it.
// Summation order ((((l0+l1)+l2)+l3)+l4)+l5 then +l6 == reference scan
// (absmax 0, verified R4/R5/R6 with the same Morton arithmetic).

using vf4 = __attribute__((ext_vector_type(4))) float;

#define L5_CELLS 262144u   // 8^5 nodes * 8 cells; tbl = L5_CELLS * 64 B

__device__ __forceinline__ unsigned spread3(unsigned x) {
    // spread 7 low bits so bit i -> bit 3i
    x &= 0x7Fu;
    x = (x | (x << 8)) & 0x0300F00Fu;
    x = (x | (x << 4)) & 0x030C30C3u;
    x = (x | (x << 2)) & 0x09249249u;
    return x;
}

// ---------------- Pass 1: build the L0..L5 prefix table + warm L6 ----------------
// starts[l]*8 (cells): C0..C6 = 0,8,72,584,4680,37448,299592.
// Thread t: cell c = t>>2, vf4-slot j = t&3. Fully coalesced in and out.
// Warm: 1M threads x 8 vf4 = all 8.4M L6 vf4s; wave k-step covers a
// contiguous 1 KB run (lanes consecutive, +64 vf4 per k).
__global__ __launch_bounds__(256) void n3_table5(
    const float* __restrict__ data,
    float* __restrict__ tbl)
{
    const unsigned t = blockIdx.x * blockDim.x + threadIdx.x;
    const unsigned c = t >> 2;
    const unsigned j = t & 3u;
    const vf4* __restrict__ dv = (const vf4*)data;

    // Issue the 8 independent long-latency warm loads FIRST so they are in
    // flight underneath the 6-level table sum. Normal (allocating) loads:
    // the whole point is L3 residency. Max addr = 1198368 + 8388607 =
    // 9586975 = last vf4 of data (in bounds).
    const unsigned base6 = 299592u * 4u + (t & ~63u) * 8u + (t & 63u);
    vf4 w0 = dv[base6 +   0u];
    vf4 w1 = dv[base6 +  64u];
    vf4 w2 = dv[base6 + 128u];
    vf4 w3 = dv[base6 + 192u];
    vf4 w4 = dv[base6 + 256u];
    vf4 w5 = dv[base6 + 320u];
    vf4 w6 = dv[base6 + 384u];
    vf4 w7 = dv[base6 + 448u];

    vf4 s =     dv[(          (c >> 15)) * 4u + j];   // L0
    s = s +     dv[(8u      + (c >> 12)) * 4u + j];   // L1
    s = s +     dv[(72u     + (c >>  9)) * 4u + j];   // L2
    s = s +     dv[(584u    + (c >>  6)) * 4u + j];   // L3
    s = s +     dv[(4680u   + (c >>  3)) * 4u + j];   // L4
    s = s +     dv[(37448u  +  c       ) * 4u + j];   // L5
    ((vf4*)tbl)[(size_t)c * 4u + j] = s;

    // Keep the warm loads alive without storing them (rule: ablation-via-
    // skip DCEs upstream ops — asm consume prevents that).
    asm volatile("" :: "v"(w0), "v"(w1), "v"(w2), "v"(w3),
                       "v"(w4), "v"(w5), "v"(w6), "v"(w7));
}

// ---------------- Pass 2: query in original qid order ----------------
__global__ __launch_bounds__(256) void n3_query_t5(
    const float* __restrict__ data,
    const float* __restrict__ tbl,
    const float* __restrict__ indices,
    const float* __restrict__ offset,
    const float* __restrict__ invradius,
    float* __restrict__ out,
    int nq)
{
    const int t = blockIdx.x * blockDim.x + threadIdx.x;
    const int q = t >> 2;        // query index
    const int j = t & 3;         // which vf4 of the 16-float cell
    if (q >= nq) return;

    const float invr = invradius[0];
    const float ox = offset[0], oy = offset[1], oz = offset[2];

    const float x = __builtin_nontemporal_load(&indices[3 * q + 0]) * invr + ox;
    const float y = __builtin_nontemporal_load(&indices[3 * q + 1]) * invr + oy;
    const float z = __builtin_nontemporal_load(&indices[3 * q + 2]) * invr + oz;

    vf4 acc = (vf4){0.0f, 0.0f, 0.0f, 0.0f};

    const bool inside = (x >= 0.0f) && (x < 1.0f) &&
                        (y >= 0.0f) && (y < 1.0f) &&
                        (z >= 0.0f) && (z < 1.0f);

    if (inside) {
        // 7-bit fixed-point coords; exact (x*128 is an exponent shift)
        const unsigned X = (unsigned)(int)(x * 128.0f);
        const unsigned Y = (unsigned)(int)(y * 128.0f);
        const unsigned Z = (unsigned)(int)(z * 128.0f);
        const unsigned M = (spread3(X) << 2) | (spread3(Y) << 1) | spread3(Z);

        const vf4 a = ((const vf4*)tbl )[((size_t)(M >> 3))      * 4 + j]; // L0..L5
        const vf4 b = ((const vf4*)data)[((size_t)(299592u + M)) * 4 + j]; // L6
        acc = a + b;
    }

    __builtin_nontemporal_store(acc, (vf4*)out + ((size_t)q * 4 + j));
}

// ---------------- Fallback: R3 direct kernel (small workspace) ----------------
__global__ __launch_bounds__(256) void n3tree_query_kernel(
    const float* __restrict__ data,
    const float* __restrict__ indices,
    const float* __restrict__ offset,
    const float* __restrict__ invradius,
    float* __restrict__ out,
    int nq)
{
    const int t = blockIdx.x * blockDim.x + threadIdx.x;
    const int q = t >> 2;
    const int j = t & 3;
    if (q >= nq) return;

    const float invr = invradius[0];
    const float ox = offset[0], oy = offset[1], oz = offset[2];

    const float x = __builtin_nontemporal_load(&indices[3 * q + 0]) * invr + ox;
    const float y = __builtin_nontemporal_load(&indices[3 * q + 1]) * invr + oy;
    const float z = __builtin_nontemporal_load(&indices[3 * q + 2]) * invr + oz;

    vf4 acc = (vf4){0.0f, 0.0f, 0.0f, 0.0f};

    const bool inside = (x >= 0.0f) && (x < 1.0f) &&
                        (y >= 0.0f) && (y < 1.0f) &&
                        (z >= 0.0f) && (z < 1.0f);

    if (inside) {
        const unsigned X = (unsigned)(int)(x * 128.0f);
        const unsigned Y = (unsigned)(int)(y * 128.0f);
        const unsigned Z = (unsigned)(int)(z * 128.0f);
        const unsigned M = (spread3(X) << 2) | (spread3(Y) << 1) | spread3(Z);

        const unsigned C[7] = {0u, 8u, 72u, 584u, 4680u, 37448u, 299592u};

        const vf4* __restrict__ dvv = (const vf4*)data;
        vf4 v0 = dvv[(C[0] + (M >> 18)) * 4 + j];
        vf4 v1 = dvv[(C[1] + (M >> 15)) * 4 + j];
        vf4 v2 = dvv[(C[2] + (M >> 12)) * 4 + j];
        vf4 v3 = dvv[(C[3] + (M >>  9)) * 4 + j];
        vf4 v4 = dvv[(C[4] + (M >>  6)) * 4 + j];
        vf4 v5 = dvv[(C[5] + (M >>  3)) * 4 + j];
        vf4 v6 = dvv[(C[6] +  M       ) * 4 + j];

        asm volatile("" : "+v"(v0), "+v"(v1), "+v"(v2), "+v"(v3),
                          "+v"(v4), "+v"(v5), "+v"(v6));

        vf4 s01 = v0 + v1;
        vf4 s23 = v2 + v3;
        vf4 s45 = v4 + v5;
        acc = (s01 + s23) + (s45 + v6);
    }

    __builtin_nontemporal_store(acc, (vf4*)out + ((size_t)q * 4 + j));
}

extern "C" void kernel_launch(void* const* d_in, const int* in_sizes, int n_in,
                              void* d_out, int out_size, void* d_ws, size_t ws_size,
                              hipStream_t stream) {
    // setup_inputs order: data, indices, offset, invradius, child
    const float* data      = (const float*)d_in[0];
    const float* indices   = (const float*)d_in[1];
    const float* offset    = (const float*)d_in[2];
    const float* invradius = (const float*)d_in[3];
    // d_in[4] (child) unused: tree is fully refined, node indices are arithmetic.
    float* out = (float*)d_out;

    const int nq = in_sizes[1] / 3;

    const size_t TBL_BYTES = (size_t)L5_CELLS * 64u;   // 16.8 MB

    if (d_ws != nullptr && ws_size >= TBL_BYTES) {
        float* tbl = (float*)d_ws;
        // Pass 1: 262144 cells * 4 vf4-slots / 256 threads = 4096 WGs
        hipLaunchKernelGGL(n3_table5, dim3(L5_CELLS * 4u / 256u), dim3(256), 0,
                           stream, data, tbl);
        // Pass 2: original-order query
        const long long threads = (long long)nq * 4;
        const int grid = (int)((threads + 255) / 256);
        hipLaunchKernelGGL(n3_query_t5, dim3(grid), dim3(256), 0, stream,
                           data, tbl, indices, offset, invradius, out, nq);
    } else {
        const int block = 256;
        const long long threads = (long long)nq * 4;
        const int grid = (int)((threads + block - 1) / block);
        hipLaunchKernelGGL(n3tree_query_kernel, dim3(grid), dim3(block), 0, stream,
                           data, indices, offset, invradius, out, nq);
    }
}

// Round 7
// 290.818 us; speedup vs baseline: 1.1136x; 1.1136x over previous
//
#include <hip/hip_runtime.h>

// N3Tree query, fully-refined octree (N=2, REFINE=6, DATA_DIM=16).
//
// R8 = R6 (best: 288.7 us) + paired-query MLP probe in the query pass.
// R7 lesson: warming L3 with a 134 MB L6 stream gave ZERO query benefit
// and cost its own bandwidth (+35 us) -> L3 residency games don't work
// for >100 MB sets here; the scattered-line premium is DRAM physics.
// R8 tests the one remaining lever: is the scattered component partially
// LATENCY-limited? Each query thread now owns TWO queries (q, q+nq/2),
// computes both Morton codes, and issues all 4 random loads (2 tbl, 2 L6)
// before consuming -> 2x in-flight random loads at equal occupancy.
// Neutral result => scattered-DRAM roofline confirmed (declare next round).
//
// Structure recap (R6): tbl[c5] = L0..L5 path sum (16.8 MB, coalesced
// build); query in ORIGINAL qid order: out[q] = tbl[M>>3] + L6[M], NT
// coalesced writes. Summation order == reference scan (absmax 0).

using vf4 = __attribute__((ext_vector_type(4))) float;

#define L5_CELLS 262144u   // 8^5 nodes * 8 cells; tbl = L5_CELLS * 64 B

__device__ __forceinline__ unsigned spread3(unsigned x) {
    // spread 7 low bits so bit i -> bit 3i
    x &= 0x7Fu;
    x = (x | (x << 8)) & 0x0300F00Fu;
    x = (x | (x << 4)) & 0x030C30C3u;
    x = (x | (x << 2)) & 0x09249249u;
    return x;
}

// ---------------- Pass 1: build the L0..L5 prefix table (R6 exact) ----------------
// starts[l]*8 (cells): C0..C6 = 0,8,72,584,4680,37448,299592.
// Thread t: cell c = t>>2, vf4-slot j = t&3. Fully coalesced in and out.
__global__ __launch_bounds__(256) void n3_table5(
    const float* __restrict__ data,
    float* __restrict__ tbl)
{
    const unsigned t = blockIdx.x * blockDim.x + threadIdx.x;
    const unsigned c = t >> 2;
    const unsigned j = t & 3u;
    const vf4* __restrict__ dv = (const vf4*)data;

    vf4 s =     dv[(          (c >> 15)) * 4u + j];   // L0
    s = s +     dv[(8u      + (c >> 12)) * 4u + j];   // L1
    s = s +     dv[(72u     + (c >>  9)) * 4u + j];   // L2
    s = s +     dv[(584u    + (c >>  6)) * 4u + j];   // L3
    s = s +     dv[(4680u   + (c >>  3)) * 4u + j];   // L4
    s = s +     dv[(37448u  +  c       ) * 4u + j];   // L5
    ((vf4*)tbl)[(size_t)c * 4u + j] = s;
}

// ---------------- Pass 2: query, 2 queries per thread (MLP probe) ----------------
__global__ __launch_bounds__(256) void n3_query_t5(
    const float* __restrict__ data,
    const float* __restrict__ tbl,
    const float* __restrict__ indices,
    const float* __restrict__ offset,
    const float* __restrict__ invradius,
    float* __restrict__ out,
    int nq)
{
    const int t = blockIdx.x * blockDim.x + threadIdx.x;
    const int qq = t >> 2;       // pair index
    const int j = t & 3;         // which vf4 of the 16-float cell
    const int half = (nq + 1) >> 1;
    if (qq >= half) return;

    const float invr = invradius[0];
    const float ox = offset[0], oy = offset[1], oz = offset[2];

    const int q0 = qq;
    const int q1 = qq + half;
    const bool has1 = (q1 < nq);

    const float x0 = __builtin_nontemporal_load(&indices[3 * q0 + 0]) * invr + ox;
    const float y0 = __builtin_nontemporal_load(&indices[3 * q0 + 1]) * invr + oy;
    const float z0 = __builtin_nontemporal_load(&indices[3 * q0 + 2]) * invr + oz;
    float x1 = 2.0f, y1 = 2.0f, z1 = 2.0f;     // outside sentinel
    if (has1) {
        x1 = __builtin_nontemporal_load(&indices[3 * q1 + 0]) * invr + ox;
        y1 = __builtin_nontemporal_load(&indices[3 * q1 + 1]) * invr + oy;
        z1 = __builtin_nontemporal_load(&indices[3 * q1 + 2]) * invr + oz;
    }

    const bool in0 = (x0 >= 0.0f) && (x0 < 1.0f) && (y0 >= 0.0f) && (y0 < 1.0f) &&
                     (z0 >= 0.0f) && (z0 < 1.0f);
    const bool in1 = (x1 >= 0.0f) && (x1 < 1.0f) && (y1 >= 0.0f) && (y1 < 1.0f) &&
                     (z1 >= 0.0f) && (z1 < 1.0f);

    unsigned M0 = 0u, M1 = 0u;
    if (in0) {
        const unsigned X = (unsigned)(int)(x0 * 128.0f);
        const unsigned Y = (unsigned)(int)(y0 * 128.0f);
        const unsigned Z = (unsigned)(int)(z0 * 128.0f);
        M0 = (spread3(X) << 2) | (spread3(Y) << 1) | spread3(Z);
    }
    if (in1) {
        const unsigned X = (unsigned)(int)(x1 * 128.0f);
        const unsigned Y = (unsigned)(int)(y1 * 128.0f);
        const unsigned Z = (unsigned)(int)(z1 * 128.0f);
        M1 = (spread3(X) << 2) | (spread3(Y) << 1) | spread3(Z);
    }

    // Issue all random loads before any consume: 4 in flight per thread.
    vf4 acc0 = (vf4){0.0f, 0.0f, 0.0f, 0.0f};
    vf4 acc1 = (vf4){0.0f, 0.0f, 0.0f, 0.0f};
    if (in0) {
        const vf4 a0 = ((const vf4*)tbl )[((size_t)(M0 >> 3))      * 4 + j];
        const vf4 b0 = ((const vf4*)data)[((size_t)(299592u + M0)) * 4 + j];
        acc0 = a0 + b0;
    }
    if (in1) {
        const vf4 a1 = ((const vf4*)tbl )[((size_t)(M1 >> 3))      * 4 + j];
        const vf4 b1 = ((const vf4*)data)[((size_t)(299592u + M1)) * 4 + j];
        acc1 = a1 + b1;
    }

    __builtin_nontemporal_store(acc0, (vf4*)out + ((size_t)q0 * 4 + j));
    if (has1)
        __builtin_nontemporal_store(acc1, (vf4*)out + ((size_t)q1 * 4 + j));
}

// ---------------- Fallback: R3 direct kernel (small workspace) ----------------
__global__ __launch_bounds__(256) void n3tree_query_kernel(
    const float* __restrict__ data,
    const float* __restrict__ indices,
    const float* __restrict__ offset,
    const float* __restrict__ invradius,
    float* __restrict__ out,
    int nq)
{
    const int t = blockIdx.x * blockDim.x + threadIdx.x;
    const int q = t >> 2;
    const int j = t & 3;
    if (q >= nq) return;

    const float invr = invradius[0];
    const float ox = offset[0], oy = offset[1], oz = offset[2];

    const float x = __builtin_nontemporal_load(&indices[3 * q + 0]) * invr + ox;
    const float y = __builtin_nontemporal_load(&indices[3 * q + 1]) * invr + oy;
    const float z = __builtin_nontemporal_load(&indices[3 * q + 2]) * invr + oz;

    vf4 acc = (vf4){0.0f, 0.0f, 0.0f, 0.0f};

    const bool inside = (x >= 0.0f) && (x < 1.0f) &&
                        (y >= 0.0f) && (y < 1.0f) &&
                        (z >= 0.0f) && (z < 1.0f);

    if (inside) {
        const unsigned X = (unsigned)(int)(x * 128.0f);
        const unsigned Y = (unsigned)(int)(y * 128.0f);
        const unsigned Z = (unsigned)(int)(z * 128.0f);
        const unsigned M = (spread3(X) << 2) | (spread3(Y) << 1) | spread3(Z);

        const unsigned C[7] = {0u, 8u, 72u, 584u, 4680u, 37448u, 299592u};

        const vf4* __restrict__ dvv = (const vf4*)data;
        vf4 v0 = dvv[(C[0] + (M >> 18)) * 4 + j];
        vf4 v1 = dvv[(C[1] + (M >> 15)) * 4 + j];
        vf4 v2 = dvv[(C[2] + (M >> 12)) * 4 + j];
        vf4 v3 = dvv[(C[3] + (M >>  9)) * 4 + j];
        vf4 v4 = dvv[(C[4] + (M >>  6)) * 4 + j];
        vf4 v5 = dvv[(C[5] + (M >>  3)) * 4 + j];
        vf4 v6 = dvv[(C[6] +  M       ) * 4 + j];

        asm volatile("" : "+v"(v0), "+v"(v1), "+v"(v2), "+v"(v3),
                          "+v"(v4), "+v"(v5), "+v"(v6));

        vf4 s01 = v0 + v1;
        vf4 s23 = v2 + v3;
        vf4 s45 = v4 + v5;
        acc = (s01 + s23) + (s45 + v6);
    }

    __builtin_nontemporal_store(acc, (vf4*)out + ((size_t)q * 4 + j));
}

extern "C" void kernel_launch(void* const* d_in, const int* in_sizes, int n_in,
                              void* d_out, int out_size, void* d_ws, size_t ws_size,
                              hipStream_t stream) {
    // setup_inputs order: data, indices, offset, invradius, child
    const float* data      = (const float*)d_in[0];
    const float* indices   = (const float*)d_in[1];
    const float* offset    = (const float*)d_in[2];
    const float* invradius = (const float*)d_in[3];
    // d_in[4] (child) unused: tree is fully refined, node indices are arithmetic.
    float* out = (float*)d_out;

    const int nq = in_sizes[1] / 3;

    const size_t TBL_BYTES = (size_t)L5_CELLS * 64u;   // 16.8 MB

    if (d_ws != nullptr && ws_size >= TBL_BYTES) {
        float* tbl = (float*)d_ws;
        // Pass 1: 262144 cells * 4 vf4-slots / 256 threads = 4096 WGs
        hipLaunchKernelGGL(n3_table5, dim3(L5_CELLS * 4u / 256u), dim3(256), 0,
                           stream, data, tbl);
        // Pass 2: paired-query pass (2 queries per thread)
        const int half = (nq + 1) >> 1;
        const long long threads = (long long)half * 4;
        const int grid = (int)((threads + 255) / 256);
        hipLaunchKernelGGL(n3_query_t5, dim3(grid), dim3(256), 0, stream,
                           data, tbl, indices, offset, invradius, out, nq);
    } else {
        const int block = 256;
        const long long threads = (long long)nq * 4;
        const int grid = (int)((threads + block - 1) / block);
        hipLaunchKernelGGL(n3tree_query_kernel, dim3(grid), dim3(block), 0, stream,
                           data, indices, offset, invradius, out, nq);
    }
}